// Round 10
// baseline (12411.243 us; speedup 1.0000x reference)
//
#include <hip/hip_runtime.h>

// Problem constants
#define BB 64       // batch
#define TT 512      // time steps
#define II 128      // input dim
#define HH 512      // hidden
#define CC 5        // out classes

// ---------------------------------------------------------------------------
// GEMM (layer-0 input projection only): out[m][n] = A[m][:]·W[n][:] + b1[n]+b2[n]
// ---------------------------------------------------------------------------
__global__ __launch_bounds__(256) void gemm_bias_kernel(
    const float* __restrict__ A, const float* __restrict__ W,
    const float* __restrict__ b1, const float* __restrict__ b2,
    float* __restrict__ out, int K)
{
    __shared__ float As[16][132];
    __shared__ float Bs[16][132];
    const int tid = threadIdx.x;
    const int bm = blockIdx.x;
    const int bn = blockIdx.y;
    const int tx = tid & 15;
    const int ty = tid >> 4;
    const int lr = tid >> 2;
    const int lk = (tid & 3) << 2;

    const float* Ab = A + (size_t)bm * 128 * K;
    const float* Wb = W + (size_t)bn * 128 * K;

    float acc[8][8];
#pragma unroll
    for (int i = 0; i < 8; ++i)
#pragma unroll
        for (int j = 0; j < 8; ++j) acc[i][j] = 0.f;

    for (int k0 = 0; k0 < K; k0 += 16) {
        float4 a0 = *(const float4*)(Ab + (size_t)lr * K + k0 + lk);
        float4 a1 = *(const float4*)(Ab + (size_t)(lr + 64) * K + k0 + lk);
        float4 w0 = *(const float4*)(Wb + (size_t)lr * K + k0 + lk);
        float4 w1 = *(const float4*)(Wb + (size_t)(lr + 64) * K + k0 + lk);
        __syncthreads();
        As[lk + 0][lr] = a0.x; As[lk + 1][lr] = a0.y; As[lk + 2][lr] = a0.z; As[lk + 3][lr] = a0.w;
        As[lk + 0][lr + 64] = a1.x; As[lk + 1][lr + 64] = a1.y; As[lk + 2][lr + 64] = a1.z; As[lk + 3][lr + 64] = a1.w;
        Bs[lk + 0][lr] = w0.x; Bs[lk + 1][lr] = w0.y; Bs[lk + 2][lr] = w0.z; Bs[lk + 3][lr] = w0.w;
        Bs[lk + 0][lr + 64] = w1.x; Bs[lk + 1][lr + 64] = w1.y; Bs[lk + 2][lr + 64] = w1.z; Bs[lk + 3][lr + 64] = w1.w;
        __syncthreads();
#pragma unroll
        for (int k = 0; k < 16; ++k) {
            float4 av0 = *(const float4*)&As[k][ty * 8];
            float4 av1 = *(const float4*)&As[k][ty * 8 + 4];
            float4 bv0 = *(const float4*)&Bs[k][tx * 8];
            float4 bv1 = *(const float4*)&Bs[k][tx * 8 + 4];
            float a[8] = {av0.x, av0.y, av0.z, av0.w, av1.x, av1.y, av1.z, av1.w};
            float b[8] = {bv0.x, bv0.y, bv0.z, bv0.w, bv1.x, bv1.y, bv1.z, bv1.w};
#pragma unroll
            for (int i = 0; i < 8; ++i)
#pragma unroll
                for (int j = 0; j < 8; ++j)
                    acc[i][j] = fmaf(a[i], b[j], acc[i][j]);
        }
    }

    const int nb = bn * 128 + tx * 8;
    float bias[8];
#pragma unroll
    for (int j = 0; j < 8; ++j) bias[j] = b1[nb + j] + b2[nb + j];
#pragma unroll
    for (int i = 0; i < 8; ++i) {
        const size_t m = (size_t)bm * 128 + ty * 8 + i;
        float4 o0 = {acc[i][0] + bias[0], acc[i][1] + bias[1], acc[i][2] + bias[2], acc[i][3] + bias[3]};
        float4 o1 = {acc[i][4] + bias[4], acc[i][5] + bias[5], acc[i][6] + bias[6], acc[i][7] + bias[7]};
        *(float4*)(out + m * HH + nb) = o0;
        *(float4*)(out + m * HH + nb + 4) = o1;
    }
}

// ---------------------------------------------------------------------------
// R10: fused 3-layer wavefront pipeline, CAPACITY-CORRECT (R9 deadlocked at
// 384 blocks > 256-resident ceiling).
// 192 blocks x 512 threads: blockIdx = l*64 + s*8 + g
//   (l=layer 0..2, s=slice 0..7 of 64 rows, g=group 0..7 of 8 batches).
// All comm partners (same l,g or adjacent l, same g) share bx%8 = g.
// CO-RESIDENCY: waves_per_eu(2,2) => 1 block/CU hard; LDS 69.7KB and VGPR
// ~190 also forbid 2/CU; 192 < 256 CUs => every block resident => spins safe.
//
// Same-layer recurrence: R8 protocol (obuf 4 slots, phase 1^(((q-1)>>2)&1),
// written[] LDS gate, self-bypass, slack-before-poll). LDS h-buffers depth 2
// (minimal: overwrite of slot (t+2)&1 is gated behind gate(t+1) which implies
// all compute of step t finished). 68-stride chunk padding keeps the
// broadcast reads conflict-free (stride 64 would alias all ksegs to 1 bank).
// Cross-layer feed: 64-deep ring pbuf, ready/epoch bit in fp32 sign (h>=0),
// epoch sign 1^((t>>6)&1), memset-0 safe. Acks every 16 steps, producer
// gates on min-ack >= t-31 => gap <= 47 < 64.
// Layers 1,2 hold W_ih slices in VGPRs (their GEMMs are gone); y history
// never touches HBM (head needs only t=511).
// ---------------------------------------------------------------------------
__global__ __launch_bounds__(512)
__attribute__((amdgpu_waves_per_eu(2, 2)))
void rnn_pipeline_kernel(
    const float* __restrict__ XP,
    const float* __restrict__ Whh0, const float* __restrict__ Whh1,
    const float* __restrict__ Whh2,
    const float* __restrict__ Wih1, const float* __restrict__ Wih2,
    const float* __restrict__ bi1, const float* __restrict__ bh1,
    const float* __restrict__ bi2, const float* __restrict__ bh2,
    float* __restrict__ yfinal,
    unsigned long long* obuf, unsigned long long* pbuf, int* ack)
{
    __shared__ float HY[2][8][544];   // own-layer h  [slot][batch][chunk*68+idx]
    __shared__ float PY[2][8][544];   // prev-layer y [slot][batch][chunk*68+idx]
    __shared__ int written[8];

    const int tid  = threadIdx.x;
    const int bx   = blockIdx.x;
    const int l    = bx >> 6;          // layer 0..2
    const int s    = (bx >> 3) & 7;    // slice 0..7
    const int g    = bx & 7;           // group 0..7 (batches 8g..8g+7)
    const int lane = tid & 63;
    const int wv   = tid >> 6;
    const int rloc = lane >> 3;
    const int kseg = lane & 7;
    const int R    = s * 64 + wv * 8 + rloc;

    const float* Whh = (l == 0) ? Whh0 : ((l == 1) ? Whh1 : Whh2);
    const float* Wih = (l == 2) ? Wih2 : Wih1;   // l==0: dummy (valid mem, unused)
    const float* wr = Whh + (size_t)R * HH + kseg * 64;
    const float* vr = Wih + (size_t)R * HH + kseg * 64;

    const float4 hA0  = *(const float4*)(wr + 0);
    const float4 hA1  = *(const float4*)(wr + 4);
    const float4 hA2  = *(const float4*)(wr + 8);
    const float4 hA3  = *(const float4*)(wr + 12);
    const float4 hA4  = *(const float4*)(wr + 16);
    const float4 hA5  = *(const float4*)(wr + 20);
    const float4 hA6  = *(const float4*)(wr + 24);
    const float4 hA7  = *(const float4*)(wr + 28);
    const float4 hA8  = *(const float4*)(wr + 32);
    const float4 hA9  = *(const float4*)(wr + 36);
    const float4 hA10 = *(const float4*)(wr + 40);
    const float4 hA11 = *(const float4*)(wr + 44);
    const float4 hA12 = *(const float4*)(wr + 48);
    const float4 hA13 = *(const float4*)(wr + 52);
    const float4 hA14 = *(const float4*)(wr + 56);
    const float4 hA15 = *(const float4*)(wr + 60);
    const float4 iA0  = *(const float4*)(vr + 0);
    const float4 iA1  = *(const float4*)(vr + 4);
    const float4 iA2  = *(const float4*)(vr + 8);
    const float4 iA3  = *(const float4*)(vr + 12);
    const float4 iA4  = *(const float4*)(vr + 16);
    const float4 iA5  = *(const float4*)(vr + 20);
    const float4 iA6  = *(const float4*)(vr + 24);
    const float4 iA7  = *(const float4*)(vr + 28);
    const float4 iA8  = *(const float4*)(vr + 32);
    const float4 iA9  = *(const float4*)(vr + 36);
    const float4 iA10 = *(const float4*)(vr + 40);
    const float4 iA11 = *(const float4*)(vr + 44);
    const float4 iA12 = *(const float4*)(vr + 48);
    const float4 iA13 = *(const float4*)(vr + 52);
    const float4 iA14 = *(const float4*)(vr + 56);
    const float4 iA15 = *(const float4*)(vr + 60);

    // obuf: per (l,g): 4 slots x 512 rows x 4 u64
    unsigned long long* ob  = obuf + (size_t)(l * 8 + g) * 8192;
    // pbuf: per (iface,g): 64 slots x 512 rows x 4 u64
    unsigned long long* pbw = pbuf + (size_t)((l < 2 ? l : 0) * 8 + g) * 131072;
    unsigned long long* pbr = pbuf + (size_t)((l > 0 ? l - 1 : 0) * 8 + g) * 131072;
    int* ackr = ack + ((l < 2 ? l : 0) * 8 + g) * 8;            // producer reads
    int* ackw = ack + ((l > 0 ? l - 1 : 0) * 8 + g) * 8 + s;    // consumer writes

    const int  ldsw    = wv * 68 + lane;           // delivery of row tid -> chunk wv
    const int  selfw   = s * 68 + wv * 8 + rloc;   // own row R -> chunk s
    const bool pub     = (kseg == 0);
    const bool foreign = (wv != s);

    float bias = 0.f;
    if (pub && l == 1) bias = bi1[R] + bh1[R];
    if (pub && l == 2) bias = bi2[R] + bh2[R];

#pragma unroll
    for (int b = 0; b < 8; ++b) HY[0][b][ldsw] = 0.f;
    if (tid < 8) written[tid] = 0;

    float x0 = bias, x1 = bias, x2 = bias, x3 = bias;
    float x4 = bias, x5 = bias, x6 = bias, x7 = bias;
    if (pub && l == 0) {
        x0 = XP[((size_t)(g * 8 + 0) * TT) * HH + R];
        x1 = XP[((size_t)(g * 8 + 1) * TT) * HH + R];
        x2 = XP[((size_t)(g * 8 + 2) * TT) * HH + R];
        x3 = XP[((size_t)(g * 8 + 3) * TT) * HH + R];
        x4 = XP[((size_t)(g * 8 + 4) * TT) * HH + R];
        x5 = XP[((size_t)(g * 8 + 5) * TT) * HH + R];
        x6 = XP[((size_t)(g * 8 + 6) * TT) * HH + R];
        x7 = XP[((size_t)(g * 8 + 7) * TT) * HH + R];
    }
    __syncthreads();   // one-time: LDS init visible

    // prologue: y_{l-1}[0] (epoch sign = 1)
    if (l > 0) {
        unsigned long long* pp = pbr + (size_t)tid * 4;
        unsigned long long u0, u1, u2, u3;
        for (;;) {
            u0 = __hip_atomic_load(pp + 0, __ATOMIC_RELAXED, __HIP_MEMORY_SCOPE_AGENT);
            u1 = __hip_atomic_load(pp + 1, __ATOMIC_RELAXED, __HIP_MEMORY_SCOPE_AGENT);
            u2 = __hip_atomic_load(pp + 2, __ATOMIC_RELAXED, __HIP_MEMORY_SCOPE_AGENT);
            u3 = __hip_atomic_load(pp + 3, __ATOMIC_RELAXED, __HIP_MEMORY_SCOPE_AGENT);
            if ((((unsigned)(u0 >> 31) & 1u) & (unsigned)(u0 >> 63) &
                 ((unsigned)(u1 >> 31) & 1u) & (unsigned)(u1 >> 63) &
                 ((unsigned)(u2 >> 31) & 1u) & (unsigned)(u2 >> 63) &
                 ((unsigned)(u3 >> 31) & 1u) & (unsigned)(u3 >> 63)) == 1u) break;
        }
        PY[0][0][ldsw] = __uint_as_float((unsigned)u0 & 0x7fffffffu);
        PY[0][1][ldsw] = __uint_as_float((unsigned)(u0 >> 32) & 0x7fffffffu);
        PY[0][2][ldsw] = __uint_as_float((unsigned)u1 & 0x7fffffffu);
        PY[0][3][ldsw] = __uint_as_float((unsigned)(u1 >> 32) & 0x7fffffffu);
        PY[0][4][ldsw] = __uint_as_float((unsigned)u2 & 0x7fffffffu);
        PY[0][5][ldsw] = __uint_as_float((unsigned)(u2 >> 32) & 0x7fffffffu);
        PY[0][6][ldsw] = __uint_as_float((unsigned)u3 & 0x7fffffffu);
        PY[0][7][ldsw] = __uint_as_float((unsigned)(u3 >> 32) & 0x7fffffffu);
    }

    for (int t = 0; t < TT; ++t) {
        // (A) own-layer + delivery gate
        if (t > 0) {
            for (;;) {
                int m = __hip_atomic_load(&written[0], __ATOMIC_RELAXED, __HIP_MEMORY_SCOPE_WORKGROUP);
#pragma unroll
                for (int c = 1; c < 8; ++c) {
                    int wc = __hip_atomic_load(&written[c], __ATOMIC_RELAXED, __HIP_MEMORY_SCOPE_WORKGROUP);
                    m = (wc < m) ? wc : m;
                }
                if (m >= t) break;
            }
            __threadfence_block();
        }
        // consumer ack (after gate: PY through step t delivered)
        if (l > 0 && tid == 0 && (t & 15) == 0)
            __hip_atomic_store(ackw, t, __ATOMIC_RELAXED, __HIP_MEMORY_SCOPE_AGENT);
        // producer flow-control gate
        if (l < 2 && t > 0 && (t & 15) == 0) {
            for (;;) {
                int m = __hip_atomic_load(ackr, __ATOMIC_RELAXED, __HIP_MEMORY_SCOPE_AGENT);
#pragma unroll
                for (int c = 1; c < 8; ++c) {
                    int a = __hip_atomic_load(ackr + c, __ATOMIC_RELAXED, __HIP_MEMORY_SCOPE_AGENT);
                    m = (a < m) ? a : m;
                }
                if (m >= t - 31) break;
            }
        }

        // (B) matmuls: 8 batches, hh (+ih for l>0)
        const int sl = t & 1;
        const float* h0 = &HY[sl][0][kseg * 68];
        const float* h1 = &HY[sl][1][kseg * 68];
        const float* h2 = &HY[sl][2][kseg * 68];
        const float* h3 = &HY[sl][3][kseg * 68];
        const float* h4 = &HY[sl][4][kseg * 68];
        const float* h5 = &HY[sl][5][kseg * 68];
        const float* h6 = &HY[sl][6][kseg * 68];
        const float* h7 = &HY[sl][7][kseg * 68];
        float A0 = 0.f, A1 = 0.f, A2 = 0.f, A3 = 0.f;
        float A4 = 0.f, A5 = 0.f, A6 = 0.f, A7 = 0.f;
#define MM8(WQ, OFF, P)                                                       \
        {                                                                     \
            float4 q0 = *(const float4*)(P##0 + (OFF));                       \
            float4 q1 = *(const float4*)(P##1 + (OFF));                       \
            float4 q2 = *(const float4*)(P##2 + (OFF));                       \
            float4 q3 = *(const float4*)(P##3 + (OFF));                       \
            float4 q4 = *(const float4*)(P##4 + (OFF));                       \
            float4 q5 = *(const float4*)(P##5 + (OFF));                       \
            float4 q6 = *(const float4*)(P##6 + (OFF));                       \
            float4 q7 = *(const float4*)(P##7 + (OFF));                       \
            A0 = fmaf(WQ.x, q0.x, A0); A0 = fmaf(WQ.y, q0.y, A0);             \
            A0 = fmaf(WQ.z, q0.z, A0); A0 = fmaf(WQ.w, q0.w, A0);             \
            A1 = fmaf(WQ.x, q1.x, A1); A1 = fmaf(WQ.y, q1.y, A1);             \
            A1 = fmaf(WQ.z, q1.z, A1); A1 = fmaf(WQ.w, q1.w, A1);             \
            A2 = fmaf(WQ.x, q2.x, A2); A2 = fmaf(WQ.y, q2.y, A2);             \
            A2 = fmaf(WQ.z, q2.z, A2); A2 = fmaf(WQ.w, q2.w, A2);             \
            A3 = fmaf(WQ.x, q3.x, A3); A3 = fmaf(WQ.y, q3.y, A3);             \
            A3 = fmaf(WQ.z, q3.z, A3); A3 = fmaf(WQ.w, q3.w, A3);             \
            A4 = fmaf(WQ.x, q4.x, A4); A4 = fmaf(WQ.y, q4.y, A4);             \
            A4 = fmaf(WQ.z, q4.z, A4); A4 = fmaf(WQ.w, q4.w, A4);             \
            A5 = fmaf(WQ.x, q5.x, A5); A5 = fmaf(WQ.y, q5.y, A5);             \
            A5 = fmaf(WQ.z, q5.z, A5); A5 = fmaf(WQ.w, q5.w, A5);             \
            A6 = fmaf(WQ.x, q6.x, A6); A6 = fmaf(WQ.y, q6.y, A6);             \
            A6 = fmaf(WQ.z, q6.z, A6); A6 = fmaf(WQ.w, q6.w, A6);             \
            A7 = fmaf(WQ.x, q7.x, A7); A7 = fmaf(WQ.y, q7.y, A7);             \
            A7 = fmaf(WQ.z, q7.z, A7); A7 = fmaf(WQ.w, q7.w, A7);             \
        }
        MM8(hA0, 0, h)   MM8(hA1, 4, h)   MM8(hA2, 8, h)   MM8(hA3, 12, h)
        MM8(hA4, 16, h)  MM8(hA5, 20, h)  MM8(hA6, 24, h)  MM8(hA7, 28, h)
        MM8(hA8, 32, h)  MM8(hA9, 36, h)  MM8(hA10, 40, h) MM8(hA11, 44, h)
        MM8(hA12, 48, h) MM8(hA13, 52, h) MM8(hA14, 56, h) MM8(hA15, 60, h)
        if (l > 0) {
            const float* p0 = &PY[sl][0][kseg * 68];
            const float* p1 = &PY[sl][1][kseg * 68];
            const float* p2 = &PY[sl][2][kseg * 68];
            const float* p3 = &PY[sl][3][kseg * 68];
            const float* p4 = &PY[sl][4][kseg * 68];
            const float* p5 = &PY[sl][5][kseg * 68];
            const float* p6 = &PY[sl][6][kseg * 68];
            const float* p7 = &PY[sl][7][kseg * 68];
            MM8(iA0, 0, p)   MM8(iA1, 4, p)   MM8(iA2, 8, p)   MM8(iA3, 12, p)
            MM8(iA4, 16, p)  MM8(iA5, 20, p)  MM8(iA6, 24, p)  MM8(iA7, 28, p)
            MM8(iA8, 32, p)  MM8(iA9, 36, p)  MM8(iA10, 40, p) MM8(iA11, 44, p)
            MM8(iA12, 48, p) MM8(iA13, 52, p) MM8(iA14, 56, p) MM8(iA15, 60, p)
        }
#undef MM8
        A0 += __shfl_xor(A0, 1); A0 += __shfl_xor(A0, 2); A0 += __shfl_xor(A0, 4);
        A1 += __shfl_xor(A1, 1); A1 += __shfl_xor(A1, 2); A1 += __shfl_xor(A1, 4);
        A2 += __shfl_xor(A2, 1); A2 += __shfl_xor(A2, 2); A2 += __shfl_xor(A2, 4);
        A3 += __shfl_xor(A3, 1); A3 += __shfl_xor(A3, 2); A3 += __shfl_xor(A3, 4);
        A4 += __shfl_xor(A4, 1); A4 += __shfl_xor(A4, 2); A4 += __shfl_xor(A4, 4);
        A5 += __shfl_xor(A5, 1); A5 += __shfl_xor(A5, 2); A5 += __shfl_xor(A5, 4);
        A6 += __shfl_xor(A6, 1); A6 += __shfl_xor(A6, 2); A6 += __shfl_xor(A6, 4);
        A7 += __shfl_xor(A7, 1); A7 += __shfl_xor(A7, 2); A7 += __shfl_xor(A7, 4);

        const int q = t + 1;
        const unsigned phO = 1u ^ (((unsigned)(q - 1) >> 2) & 1u);
        const unsigned phP = 1u ^ (((unsigned)t >> 6) & 1u);

        if (pub) {
            const float y0 = fmaxf(A0 + x0, 0.f);
            const float y1 = fmaxf(A1 + x1, 0.f);
            const float y2 = fmaxf(A2 + x2, 0.f);
            const float y3 = fmaxf(A3 + x3, 0.f);
            const float y4 = fmaxf(A4 + x4, 0.f);
            const float y5 = fmaxf(A5 + x5, 0.f);
            const float y6 = fmaxf(A6 + x6, 0.f);
            const float y7 = fmaxf(A7 + x7, 0.f);
#define PACK(a, b, ph) ((unsigned long long)(__float_as_uint(a) | ((ph) << 31)) | \
                        ((unsigned long long)(__float_as_uint(b) | ((ph) << 31)) << 32))
            if (q < TT) {
                unsigned long long* op = ob + (size_t)(q & 3) * 2048 + R * 4;
                __hip_atomic_store(op + 0, PACK(y0, y1, phO), __ATOMIC_RELAXED, __HIP_MEMORY_SCOPE_AGENT);
                __hip_atomic_store(op + 1, PACK(y2, y3, phO), __ATOMIC_RELAXED, __HIP_MEMORY_SCOPE_AGENT);
                __hip_atomic_store(op + 2, PACK(y4, y5, phO), __ATOMIC_RELAXED, __HIP_MEMORY_SCOPE_AGENT);
                __hip_atomic_store(op + 3, PACK(y6, y7, phO), __ATOMIC_RELAXED, __HIP_MEMORY_SCOPE_AGENT);
                HY[q & 1][0][selfw] = y0; HY[q & 1][1][selfw] = y1;
                HY[q & 1][2][selfw] = y2; HY[q & 1][3][selfw] = y3;
                HY[q & 1][4][selfw] = y4; HY[q & 1][5][selfw] = y5;
                HY[q & 1][6][selfw] = y6; HY[q & 1][7][selfw] = y7;
            }
            if (l < 2) {
                unsigned long long* pp = pbw + (size_t)(t & 63) * 2048 + R * 4;
                __hip_atomic_store(pp + 0, PACK(y0, y1, phP), __ATOMIC_RELAXED, __HIP_MEMORY_SCOPE_AGENT);
                __hip_atomic_store(pp + 1, PACK(y2, y3, phP), __ATOMIC_RELAXED, __HIP_MEMORY_SCOPE_AGENT);
                __hip_atomic_store(pp + 2, PACK(y4, y5, phP), __ATOMIC_RELAXED, __HIP_MEMORY_SCOPE_AGENT);
                __hip_atomic_store(pp + 3, PACK(y6, y7, phP), __ATOMIC_RELAXED, __HIP_MEMORY_SCOPE_AGENT);
            }
#undef PACK
            if (l == 2 && t == TT - 1) {
                yfinal[(size_t)(g * 8 + 0) * HH + R] = y0;
                yfinal[(size_t)(g * 8 + 1) * HH + R] = y1;
                yfinal[(size_t)(g * 8 + 2) * HH + R] = y2;
                yfinal[(size_t)(g * 8 + 3) * HH + R] = y3;
                yfinal[(size_t)(g * 8 + 4) * HH + R] = y4;
                yfinal[(size_t)(g * 8 + 5) * HH + R] = y5;
                yfinal[(size_t)(g * 8 + 6) * HH + R] = y6;
                yfinal[(size_t)(g * 8 + 7) * HH + R] = y7;
            }
            // slack vmem BEFORE the polls (drains inside poll vmcnt wait)
            if (l == 0 && q < TT) {
                x0 = XP[((size_t)(g * 8 + 0) * TT + q) * HH + R];
                x1 = XP[((size_t)(g * 8 + 1) * TT + q) * HH + R];
                x2 = XP[((size_t)(g * 8 + 2) * TT + q) * HH + R];
                x3 = XP[((size_t)(g * 8 + 3) * TT + q) * HH + R];
                x4 = XP[((size_t)(g * 8 + 4) * TT + q) * HH + R];
                x5 = XP[((size_t)(g * 8 + 5) * TT + q) * HH + R];
                x6 = XP[((size_t)(g * 8 + 6) * TT + q) * HH + R];
                x7 = XP[((size_t)(g * 8 + 7) * TT + q) * HH + R];
            }
        }

        if (q < TT) {
            if (foreign) {   // own-layer poll (row tid)
                unsigned long long* op = ob + (size_t)(q & 3) * 2048 + (size_t)tid * 4;
                unsigned long long u0, u1, u2, u3;
                for (;;) {
                    u0 = __hip_atomic_load(op + 0, __ATOMIC_RELAXED, __HIP_MEMORY_SCOPE_AGENT);
                    u1 = __hip_atomic_load(op + 1, __ATOMIC_RELAXED, __HIP_MEMORY_SCOPE_AGENT);
                    u2 = __hip_atomic_load(op + 2, __ATOMIC_RELAXED, __HIP_MEMORY_SCOPE_AGENT);
                    u3 = __hip_atomic_load(op + 3, __ATOMIC_RELAXED, __HIP_MEMORY_SCOPE_AGENT);
                    unsigned ok = (((unsigned)(u0 >> 31) & 1u) ^ phO) | ((unsigned)(u0 >> 63) ^ phO) |
                                  (((unsigned)(u1 >> 31) & 1u) ^ phO) | ((unsigned)(u1 >> 63) ^ phO) |
                                  (((unsigned)(u2 >> 31) & 1u) ^ phO) | ((unsigned)(u2 >> 63) ^ phO) |
                                  (((unsigned)(u3 >> 31) & 1u) ^ phO) | ((unsigned)(u3 >> 63) ^ phO);
                    if (ok == 0u) break;
                }
                HY[q & 1][0][ldsw] = __uint_as_float((unsigned)u0 & 0x7fffffffu);
                HY[q & 1][1][ldsw] = __uint_as_float((unsigned)(u0 >> 32) & 0x7fffffffu);
                HY[q & 1][2][ldsw] = __uint_as_float((unsigned)u1 & 0x7fffffffu);
                HY[q & 1][3][ldsw] = __uint_as_float((unsigned)(u1 >> 32) & 0x7fffffffu);
                HY[q & 1][4][ldsw] = __uint_as_float((unsigned)u2 & 0x7fffffffu);
                HY[q & 1][5][ldsw] = __uint_as_float((unsigned)(u2 >> 32) & 0x7fffffffu);
                HY[q & 1][6][ldsw] = __uint_as_float((unsigned)u3 & 0x7fffffffu);
                HY[q & 1][7][ldsw] = __uint_as_float((unsigned)(u3 >> 32) & 0x7fffffffu);
            }
            if (l > 0) {     // prev-layer poll for step q (row tid)
                const unsigned phQ = 1u ^ (((unsigned)q >> 6) & 1u);
                unsigned long long* pp = pbr + (size_t)(q & 63) * 2048 + (size_t)tid * 4;
                unsigned long long u0, u1, u2, u3;
                for (;;) {
                    u0 = __hip_atomic_load(pp + 0, __ATOMIC_RELAXED, __HIP_MEMORY_SCOPE_AGENT);
                    u1 = __hip_atomic_load(pp + 1, __ATOMIC_RELAXED, __HIP_MEMORY_SCOPE_AGENT);
                    u2 = __hip_atomic_load(pp + 2, __ATOMIC_RELAXED, __HIP_MEMORY_SCOPE_AGENT);
                    u3 = __hip_atomic_load(pp + 3, __ATOMIC_RELAXED, __HIP_MEMORY_SCOPE_AGENT);
                    unsigned ok = (((unsigned)(u0 >> 31) & 1u) ^ phQ) | ((unsigned)(u0 >> 63) ^ phQ) |
                                  (((unsigned)(u1 >> 31) & 1u) ^ phQ) | ((unsigned)(u1 >> 63) ^ phQ) |
                                  (((unsigned)(u2 >> 31) & 1u) ^ phQ) | ((unsigned)(u2 >> 63) ^ phQ) |
                                  (((unsigned)(u3 >> 31) & 1u) ^ phQ) | ((unsigned)(u3 >> 63) ^ phQ);
                    if (ok == 0u) break;
                }
                PY[q & 1][0][ldsw] = __uint_as_float((unsigned)u0 & 0x7fffffffu);
                PY[q & 1][1][ldsw] = __uint_as_float((unsigned)(u0 >> 32) & 0x7fffffffu);
                PY[q & 1][2][ldsw] = __uint_as_float((unsigned)u1 & 0x7fffffffu);
                PY[q & 1][3][ldsw] = __uint_as_float((unsigned)(u1 >> 32) & 0x7fffffffu);
                PY[q & 1][4][ldsw] = __uint_as_float((unsigned)u2 & 0x7fffffffu);
                PY[q & 1][5][ldsw] = __uint_as_float((unsigned)(u2 >> 32) & 0x7fffffffu);
                PY[q & 1][6][ldsw] = __uint_as_float((unsigned)u3 & 0x7fffffffu);
                PY[q & 1][7][ldsw] = __uint_as_float((unsigned)(u3 >> 32) & 0x7fffffffu);
            }
            __threadfence_block();
            if (lane == 0)
                __hip_atomic_store(&written[wv], q, __ATOMIC_RELAXED, __HIP_MEMORY_SCOPE_WORKGROUP);
        }
    }
}

// ---------------------------------------------------------------------------
// Head: out[b][c] = yfinal[b][:]·W_out[c][:] + b_out[c]
// ---------------------------------------------------------------------------
__global__ __launch_bounds__(64) void head_kernel(
    const float* __restrict__ yfinal, const float* __restrict__ Wout,
    const float* __restrict__ bout, float* __restrict__ out)
{
    const int bc = blockIdx.x;
    const int b = bc / CC, c = bc % CC;
    const int lane = threadIdx.x;
    const float* yrow = yfinal + (size_t)b * HH;
    const float* wrow = Wout + (size_t)c * HH;
    float s = 0.f;
#pragma unroll
    for (int i = 0; i < HH / 64; ++i)
        s = fmaf(yrow[lane + 64 * i], wrow[lane + 64 * i], s);
#pragma unroll
    for (int off = 32; off > 0; off >>= 1) s += __shfl_down(s, off);
    if (lane == 0) out[bc] = s + bout[c];
}

// ---------------------------------------------------------------------------
extern "C" void kernel_launch(void* const* d_in, const int* in_sizes, int n_in,
                              void* d_out, int out_size, void* d_ws, size_t ws_size,
                              hipStream_t stream)
{
    const float* x = (const float*)d_in[0];
    const float* W_ih[3] = {(const float*)d_in[1], (const float*)d_in[5], (const float*)d_in[9]};
    const float* W_hh[3] = {(const float*)d_in[2], (const float*)d_in[6], (const float*)d_in[10]};
    const float* b_ih[3] = {(const float*)d_in[3], (const float*)d_in[7], (const float*)d_in[11]};
    const float* b_hh[3] = {(const float*)d_in[4], (const float*)d_in[8], (const float*)d_in[12]};
    const float* W_out = (const float*)d_in[13];
    const float* b_out = (const float*)d_in[14];
    float* out = (float*)d_out;

    // workspace: XP (64MB) | yfinal (128KB) | obuf (1.5MB) | pbuf (16MB) | ack
    float* ws = (float*)d_ws;
    float* XP = ws;
    float* yfinal = ws + (size_t)BB * TT * HH;
    unsigned long long* obuf = (unsigned long long*)(yfinal + (size_t)BB * HH);
    // obuf: 3 layers * 8 g * (4 slots * 512 rows * 4 u64 = 8192)
    unsigned long long* pbuf = obuf + (size_t)3 * 8 * 8192;
    // pbuf: 2 ifaces * 8 g * (64 slots * 512 rows * 4 u64 = 131072)
    int* ack = (int*)(pbuf + (size_t)2 * 8 * 131072);   // 2*8*8 ints

    const size_t zero_bytes = ((size_t)3 * 8 * 8192 + (size_t)2 * 8 * 131072) * 8
                            + (size_t)2 * 8 * 8 * sizeof(int);
    (void)hipMemsetAsync(obuf, 0, zero_bytes, stream);

    // layer-0 input projection
    gemm_bias_kernel<<<dim3(256, 4), 256, 0, stream>>>(x, W_ih[0], b_ih[0], b_hh[0], XP, II);
    // fused 3-layer wavefront pipeline (192 blocks: ALL co-resident at 1/CU)
    rnn_pipeline_kernel<<<192, 512, 0, stream>>>(
        XP, W_hh[0], W_hh[1], W_hh[2], W_ih[1], W_ih[2],
        b_ih[1], b_hh[1], b_ih[2], b_hh[2], yfinal, obuf, pbuf, ack);
    // head
    head_kernel<<<BB * CC, 64, 0, stream>>>(yfinal, W_out, b_out, out);
}